// Round 1
// baseline (8543.852 us; speedup 1.0000x reference)
//
#include <hip/hip_runtime.h>
#include <math.h>

#define ROWS 8192   // B*S
#define DIM  1024
#define NH   8
#define DKh  128
#define DVh  128
#define DFF_ 4096
#define EPSF 1e-6f

__device__ __forceinline__ float siluf(float x) {
    return x / (1.0f + expf(-x));
}

// ---------------- RMSNorm: y = x * rsqrt(mean(x^2)+eps), row = 1024 ----------------
__global__ void rmsnorm_kernel(const float* __restrict__ x, float* __restrict__ y) {
    int row = blockIdx.x;
    int tid = threadIdx.x;            // 256 threads, one float4 each
    const float4* x4 = (const float4*)(x + (size_t)row * DIM);
    float4 v = x4[tid];
    float ss = v.x * v.x + v.y * v.y + v.z * v.z + v.w * v.w;
#pragma unroll
    for (int m = 1; m < 64; m <<= 1) ss += __shfl_xor(ss, m, 64);
    __shared__ float wss[4];
    if ((tid & 63) == 0) wss[tid >> 6] = ss;
    __syncthreads();
    float tot = wss[0] + wss[1] + wss[2] + wss[3];
    float r = rsqrtf(tot * (1.0f / 1024.0f) + EPSF);
    float4 o;
    o.x = v.x * r; o.y = v.y * r; o.z = v.z * r; o.w = v.w * r;
    ((float4*)(y + (size_t)row * DIM))[tid] = o;
}

// ---------------- Tiled fp32 GEMM: C[M,N] = A[M,K] @ B[K,N]  ----------------
// EPI: 0 = none, 1 = silu, 2 = res + acc, 3 = relu(acc)^2
template <int EPI>
__global__ __launch_bounds__(256) void gemm_kernel(
    const float* __restrict__ A, const float* __restrict__ B,
    float* __restrict__ C, const float* __restrict__ res,
    int M, int N, int K) {
    __shared__ __align__(16) float As[16][68];  // transposed A tile, padded
    __shared__ __align__(16) float Bs[16][64];
    int tid = threadIdx.x;
    int bm = blockIdx.y * 64, bn = blockIdx.x * 64;

    int aRow = tid >> 2, aK = (tid & 3) << 2;     // A: 64 rows x 16 k
    int bK = tid >> 4, bN = (tid & 15) << 2;      // B: 16 k x 64 cols
    int tm = (tid >> 4) << 2, tn = (tid & 15) << 2;

    float acc[4][4];
#pragma unroll
    for (int i = 0; i < 4; i++)
#pragma unroll
        for (int j = 0; j < 4; j++) acc[i][j] = 0.0f;

    const float* Aptr = A + (size_t)(bm + aRow) * K + aK;
    const float* Bptr = B + (size_t)bK * N + bn + bN;

    for (int kt = 0; kt < K; kt += 16) {
        float4 av = *(const float4*)(Aptr + kt);
        float4 bv = *(const float4*)(Bptr + (size_t)kt * N);
        As[aK + 0][aRow] = av.x;
        As[aK + 1][aRow] = av.y;
        As[aK + 2][aRow] = av.z;
        As[aK + 3][aRow] = av.w;
        *(float4*)&Bs[bK][bN] = bv;
        __syncthreads();
#pragma unroll
        for (int kk = 0; kk < 16; kk++) {
            float4 a4 = *(const float4*)&As[kk][tm];
            float4 b4 = *(const float4*)&Bs[kk][tn];
            float a_[4] = {a4.x, a4.y, a4.z, a4.w};
            float b_[4] = {b4.x, b4.y, b4.z, b4.w};
#pragma unroll
            for (int i = 0; i < 4; i++)
#pragma unroll
                for (int j = 0; j < 4; j++) acc[i][j] += a_[i] * b_[j];
        }
        __syncthreads();
    }

#pragma unroll
    for (int i = 0; i < 4; i++) {
        size_t idx = (size_t)(bm + tm + i) * N + bn + tn;
        float o[4] = {acc[i][0], acc[i][1], acc[i][2], acc[i][3]};
        if (EPI == 1) {
#pragma unroll
            for (int j = 0; j < 4; j++) o[j] = siluf(o[j]);
        } else if (EPI == 2) {
            float4 rv = *(const float4*)&res[idx];
            o[0] += rv.x; o[1] += rv.y; o[2] += rv.z; o[3] += rv.w;
        } else if (EPI == 3) {
#pragma unroll
            for (int j = 0; j < 4; j++) {
                float t = fmaxf(o[j], 0.0f);
                o[j] = t * t;
            }
        }
        float4 ov = {o[0], o[1], o[2], o[3]};
        *(float4*)&C[idx] = ov;
    }
}

// ---------------- l2norm over 128-chunks (in-place), row = 1024 ----------------
__global__ void l2norm_kernel(float* __restrict__ x) {
    int row = blockIdx.x;
    int tid = threadIdx.x;  // 256 threads; lanes [32g..32g+31] own one 128-chunk
    float4* p = (float4*)(x + (size_t)row * DIM);
    float4 v = p[tid];
    float ss = v.x * v.x + v.y * v.y + v.z * v.z + v.w * v.w;
#pragma unroll
    for (int m = 1; m < 32; m <<= 1) ss += __shfl_xor(ss, m, 32);
    float r = rsqrtf(ss + EPSF);  // sum, not mean
    v.x *= r; v.y *= r; v.z *= r; v.w *= r;
    p[tid] = v;
}

// ---------------- gated RMSNorm: o = rms(o)*w*silu(gate), chunk=128 ----------------
__global__ void gating_kernel(float* __restrict__ o, const float* __restrict__ gate,
                              const float* __restrict__ w) {
    int row = blockIdx.x;
    int tid = threadIdx.x;  // 256
    float4* op = (float4*)(o + (size_t)row * DIM);
    const float4* gp = (const float4*)(gate + (size_t)row * DIM);
    float4 v = op[tid];
    float ss = v.x * v.x + v.y * v.y + v.z * v.z + v.w * v.w;
#pragma unroll
    for (int m = 1; m < 32; m <<= 1) ss += __shfl_xor(ss, m, 32);
    float r = rsqrtf(ss * (1.0f / 128.0f) + EPSF);
    float4 g = gp[tid];
    float4 wv = ((const float4*)w)[tid & 31];
    float4 out;
    out.x = v.x * r * wv.x * siluf(g.x);
    out.y = v.y * r * wv.y * siluf(g.y);
    out.z = v.z * r * wv.z * siluf(g.z);
    out.w = v.w * r * wv.w * siluf(g.w);
    op[tid] = out;
}

// ---------------- small projections: beta = sigm(h@Wb), alpha = exp(g) ----------------
__global__ void smallproj_kernel(const float* __restrict__ hbuf,
                                 const float* __restrict__ Wb, const float* __restrict__ Wa,
                                 const float* __restrict__ A_log, const float* __restrict__ dt_bias,
                                 float* __restrict__ Alpha, float* __restrict__ Beta) {
    int row = blockIdx.x;
    int tid = threadIdx.x;  // 128
    __shared__ __align__(16) float hrow[1024];
    __shared__ float part[128];
    const float4* h4 = (const float4*)(hbuf + (size_t)row * DIM);
    ((float4*)hrow)[tid] = h4[tid];
    ((float4*)hrow)[tid + 128] = h4[tid + 128];
    __syncthreads();
    int out = tid & 15, slice = tid >> 4;
    const float* W = (out < 8) ? Wb : Wa;
    int col = out & 7;
    int k0 = slice * 128;
    float p = 0.0f;
    for (int kk = 0; kk < 128; kk++) p += hrow[k0 + kk] * W[(size_t)(k0 + kk) * 8 + col];
    part[tid] = p;
    __syncthreads();
    if (tid < 16) {
        float sum = 0.0f;
#pragma unroll
        for (int sl = 0; sl < 8; sl++) sum += part[sl * 16 + tid];
        if (tid < 8) {
            Beta[(size_t)row * 8 + tid] = 1.0f / (1.0f + expf(-sum));
        } else {
            int hh = tid - 8;
            float xg = sum + dt_bias[hh];
            float sp = fmaxf(xg, 0.0f) + log1pf(expf(-fabsf(xg)));
            Alpha[(size_t)row * 8 + hh] = expf(-expf(A_log[hh]) * sp);
        }
    }
}

// ---------------- gated delta-rule scan ----------------
// One block per (b,h); thread = dv column; state S[dk][dv] column in registers.
__global__ __launch_bounds__(128, 1) void scan_kernel(
    const float* __restrict__ Q, const float* __restrict__ Kb,
    const float* __restrict__ V, const float* __restrict__ Alpha,
    const float* __restrict__ Beta, float* __restrict__ O) {
    int bh = blockIdx.x;
    int b = bh >> 3, h = bh & 7;
    int tid = threadIdx.x;  // dv
    __shared__ __align__(16) float k_lds[128];
    __shared__ __align__(16) float q_lds[128];
    float s[128];
#pragma unroll
    for (int i = 0; i < 128; i++) s[i] = 0.0f;
    const float scale = 0.08838834764831845f;  // DK^-0.5
    size_t rowbase = (size_t)b * 2048 * DIM + (size_t)h * DKh;

    for (int t = 0; t < 2048; t++) {
        size_t base = rowbase + (size_t)t * DIM;
        k_lds[tid] = Kb[base + tid];
        q_lds[tid] = Q[base + tid];
        float vv = V[base + tid];
        int r = b * 2048 + t;
        float a = Alpha[(size_t)r * 8 + h];
        float bt = Beta[(size_t)r * 8 + h];
        __syncthreads();

        const float4* k4 = (const float4*)k_lds;
        const float4* q4 = (const float4*)q_lds;
        float kv = 0.0f;
#pragma unroll
        for (int i = 0; i < 32; i++) {
            float4 kk = k4[i];
            kv += kk.x * s[4 * i + 0] + kk.y * s[4 * i + 1] +
                  kk.z * s[4 * i + 2] + kk.w * s[4 * i + 3];
        }
        float delta = (vv - a * kv) * bt;
        float oacc = 0.0f;
#pragma unroll
        for (int i = 0; i < 32; i++) {
            float4 kk = k4[i];
            float4 qq = q4[i];
            s[4 * i + 0] = a * s[4 * i + 0] + kk.x * delta; oacc += qq.x * s[4 * i + 0];
            s[4 * i + 1] = a * s[4 * i + 1] + kk.y * delta; oacc += qq.y * s[4 * i + 1];
            s[4 * i + 2] = a * s[4 * i + 2] + kk.z * delta; oacc += qq.z * s[4 * i + 2];
            s[4 * i + 3] = a * s[4 * i + 3] + kk.w * delta; oacc += qq.w * s[4 * i + 3];
        }
        O[base + tid] = oacc * scale;
        __syncthreads();
    }
}

extern "C" void kernel_launch(void* const* d_in, const int* in_sizes, int n_in,
                              void* d_out, int out_size, void* d_ws, size_t ws_size,
                              hipStream_t stream) {
    const float* x      = (const float*)d_in[0];
    const float* Wq     = (const float*)d_in[1];
    const float* Wk     = (const float*)d_in[2];
    const float* Wv     = (const float*)d_in[3];
    const float* Wb     = (const float*)d_in[4];
    const float* Wa     = (const float*)d_in[5];
    const float* A_log  = (const float*)d_in[6];
    const float* dt_b   = (const float*)d_in[7];
    const float* Wg     = (const float*)d_in[8];
    const float* o_norm = (const float*)d_in[9];
    const float* Wo     = (const float*)d_in[10];
    const float* W_fc   = (const float*)d_in[11];
    const float* W_proj = (const float*)d_in[12];
    float* out = (float*)d_out;

    const size_t MAT = (size_t)ROWS * DIM;  // 8,388,608
    float* ws   = (float*)d_ws;
    float* h    = ws;
    float* q    = ws + MAT;
    float* k    = ws + 2 * MAT;
    float* v    = ws + 3 * MAT;
    float* gate = ws + 4 * MAT;
    float* o    = ws + 5 * MAT;
    float* alpha= ws + 6 * MAT;
    float* beta = alpha + (size_t)ROWS * NH;
    float* fc   = q;  // reuse q..gate region: 4*MAT = 32M floats, exactly ROWS*DFF

    // 1. h = rms_norm(x)
    rmsnorm_kernel<<<ROWS, 256, 0, stream>>>(x, h);

    // 2. projections
    dim3 g1(DIM / 64, ROWS / 64);
    gemm_kernel<1><<<g1, 256, 0, stream>>>(h, Wq, q, nullptr, ROWS, DIM, DIM);      // silu
    gemm_kernel<1><<<g1, 256, 0, stream>>>(h, Wk, k, nullptr, ROWS, DIM, DIM);      // silu
    gemm_kernel<1><<<g1, 256, 0, stream>>>(h, Wv, v, nullptr, ROWS, DIM, DIM);      // silu
    gemm_kernel<0><<<g1, 256, 0, stream>>>(h, Wg, gate, nullptr, ROWS, DIM, DIM);   // raw

    // 3. l2norm on q, k (per-head 128 chunks)
    l2norm_kernel<<<ROWS, 256, 0, stream>>>(q);
    l2norm_kernel<<<ROWS, 256, 0, stream>>>(k);

    // 4. beta/alpha
    smallproj_kernel<<<ROWS, 128, 0, stream>>>(h, Wb, Wa, A_log, dt_b, alpha, beta);

    // 5. sequential delta-rule scan
    scan_kernel<<<32, 128, 0, stream>>>(q, k, v, alpha, beta, o);

    // 6. gated RMSNorm (in-place on o)
    gating_kernel<<<ROWS, 256, 0, stream>>>(o, gate, o_norm);

    // 7. attn out + residual: d_out = x + o @ Wo
    gemm_kernel<2><<<g1, 256, 0, stream>>>(o, Wo, out, x, ROWS, DIM, DIM);

    // 8. m = rms_norm(d_out) -> h (reuse)
    rmsnorm_kernel<<<ROWS, 256, 0, stream>>>(out, h);

    // 9. fc = relu(m @ W_fc)^2
    dim3 g2(DFF_ / 64, ROWS / 64);
    gemm_kernel<3><<<g2, 256, 0, stream>>>(h, W_fc, fc, nullptr, ROWS, DFF_, DIM);

    // 10. d_out = d_out + fc @ W_proj
    gemm_kernel<2><<<g1, 256, 0, stream>>>(fc, W_proj, out, out, ROWS, DIM, DFF_);
}

// Round 2
// 1625.421 us; speedup vs baseline: 5.2564x; 5.2564x over previous
//
#include <hip/hip_runtime.h>
#include <math.h>
#include <stdint.h>

#define ROWS 8192   // B*S
#define DIM  1024
#define NH   8
#define DFF_ 4096
#define EPSF 1e-6f

typedef __attribute__((ext_vector_type(8))) short short8;
typedef __attribute__((ext_vector_type(4))) float f32x4;

__device__ __forceinline__ float siluf(float x) {
    return x / (1.0f + expf(-x));
}
__device__ __forceinline__ unsigned short f2bf(float f) {
    uint32_t u = __float_as_uint(f);
    uint32_t r = (u + 0x7FFFu + ((u >> 16) & 1u)) >> 16;
    return (unsigned short)r;
}
__device__ __forceinline__ float bf2f(unsigned short u) {
    return __uint_as_float(((uint32_t)u) << 16);
}

// async global->LDS 16B (wave-uniform LDS base + lane*16)
__device__ __forceinline__ void async16(const void* g, void* l) {
    __builtin_amdgcn_global_load_lds(
        (const __attribute__((address_space(1))) uint32_t*)g,
        (__attribute__((address_space(3))) uint32_t*)l, 16, 0, 0);
}

// ---------------- RMSNorm -> bf16 out ----------------
__global__ void rmsnorm_bf16_kernel(const float* __restrict__ x, unsigned short* __restrict__ y) {
    int row = blockIdx.x;
    int tid = threadIdx.x;  // 256 threads, one float4 each
    const float4* x4 = (const float4*)(x + (size_t)row * DIM);
    float4 v = x4[tid];
    float ss = v.x * v.x + v.y * v.y + v.z * v.z + v.w * v.w;
#pragma unroll
    for (int m = 1; m < 64; m <<= 1) ss += __shfl_xor(ss, m, 64);
    __shared__ float wss[4];
    if ((tid & 63) == 0) wss[tid >> 6] = ss;
    __syncthreads();
    float tot = wss[0] + wss[1] + wss[2] + wss[3];
    float r = rsqrtf(tot * (1.0f / 1024.0f) + EPSF);
    ushort4 o;
    o.x = f2bf(v.x * r); o.y = f2bf(v.y * r); o.z = f2bf(v.z * r); o.w = f2bf(v.w * r);
    ((ushort4*)(y + (size_t)row * DIM))[tid] = o;
}

// ---------------- fp32 -> bf16 transpose: W[K,N] -> WT[N,K] ----------------
__global__ void transpose_bf16_kernel(const float* __restrict__ W, unsigned short* __restrict__ WT,
                                      int K, int N) {
    __shared__ float tile[32][33];
    int n0 = blockIdx.x * 32, k0 = blockIdx.y * 32;
    int tx = threadIdx.x & 31, ty = threadIdx.x >> 5;  // 256 threads: 32 x 8
#pragma unroll
    for (int r = 0; r < 32; r += 8)
        tile[ty + r][tx] = W[(size_t)(k0 + ty + r) * N + n0 + tx];
    __syncthreads();
#pragma unroll
    for (int r = 0; r < 32; r += 8)
        WT[(size_t)(n0 + ty + r) * K + k0 + tx] = f2bf(tile[tx][ty + r]);
}

// ---------------- bf16 MFMA GEMM: C[M,N] = A[M,K] @ BT[N,K]^T ----------------
// EPI: 0 none(f32), 1 silu(f32), 2 res+acc(f32), 3 relu^2 -> bf16
template <int EPI, typename CT>
__global__ __launch_bounds__(256) void mfma_gemm(
    const unsigned short* __restrict__ A, const unsigned short* __restrict__ BT,
    CT* __restrict__ C, const float* __restrict__ res, int M, int N, int K) {
    __shared__ __align__(16) unsigned short As[128 * 32];
    __shared__ __align__(16) unsigned short Bs[128 * 32];
    int tid = threadIdx.x;
    int w = tid >> 6, lane = tid & 63;
    int bm = blockIdx.y * 128, bn = blockIdx.x * 128;
    int wm = (w >> 1) * 64, wn = (w & 1) * 64;

    int srow = tid >> 2;           // 0..63
    int skb = (tid & 3) * 8;       // ushort offset in row (16B chunks)
    const unsigned short* Ag = A + (size_t)(bm + srow) * K + skb;
    const unsigned short* Bg = BT + (size_t)(bn + srow) * K + skb;

    f32x4 acc[4][4] = {};

    int lr = lane & 15;
    int lk = (lane >> 4) * 8;

    for (int kt = 0; kt < K; kt += 32) {
        async16(Ag + kt, As + w * 512);
        async16(Ag + kt + (size_t)64 * K, As + 2048 + w * 512);
        async16(Bg + kt, Bs + w * 512);
        async16(Bg + kt + (size_t)64 * K, Bs + 2048 + w * 512);
        __syncthreads();  // drains vmcnt+lgkmcnt
        short8 af[4], bf[4];
#pragma unroll
        for (int i = 0; i < 4; i++) {
            af[i] = *(const short8*)&As[(wm + i * 16 + lr) * 32 + lk];
            bf[i] = *(const short8*)&Bs[(wn + i * 16 + lr) * 32 + lk];
        }
#pragma unroll
        for (int i = 0; i < 4; i++)
#pragma unroll
            for (int j = 0; j < 4; j++)
                acc[i][j] = __builtin_amdgcn_mfma_f32_16x16x32_bf16(af[i], bf[j], acc[i][j], 0, 0, 0);
        __syncthreads();
    }

#pragma unroll
    for (int i = 0; i < 4; i++) {
        int gr0 = bm + wm + i * 16 + (lane >> 4) * 4;
#pragma unroll
        for (int j = 0; j < 4; j++) {
            int gc = bn + wn + j * 16 + lr;
#pragma unroll
            for (int r = 0; r < 4; r++) {
                float v = acc[i][j][r];
                size_t idx = (size_t)(gr0 + r) * N + gc;
                if (EPI == 1) v = siluf(v);
                else if (EPI == 2) v += res[idx];
                else if (EPI == 3) { float t = fmaxf(v, 0.0f); v = t * t; }
                if constexpr (sizeof(CT) == 2) C[idx] = (CT)f2bf(v);
                else C[idx] = v;
            }
        }
    }
}

// ---------------- l2norm over 128-chunks (in-place fp32) ----------------
__global__ void l2norm_kernel(float* __restrict__ x) {
    int row = blockIdx.x;
    int tid = threadIdx.x;  // 256
    float4* p = (float4*)(x + (size_t)row * DIM);
    float4 v = p[tid];
    float ss = v.x * v.x + v.y * v.y + v.z * v.z + v.w * v.w;
#pragma unroll
    for (int m = 1; m < 32; m <<= 1) ss += __shfl_xor(ss, m, 32);
    float r = rsqrtf(ss + EPSF);
    v.x *= r; v.y *= r; v.z *= r; v.w *= r;
    p[tid] = v;
}

// ---------------- gated RMSNorm -> bf16: ob = rms128(o)*w*silu(gate) ----------------
__global__ void gating_kernel(const float* __restrict__ o, const float* __restrict__ gate,
                              const float* __restrict__ w, unsigned short* __restrict__ ob) {
    int row = blockIdx.x;
    int tid = threadIdx.x;  // 256
    const float4* op = (const float4*)(o + (size_t)row * DIM);
    const float4* gp = (const float4*)(gate + (size_t)row * DIM);
    float4 v = op[tid];
    float ss = v.x * v.x + v.y * v.y + v.z * v.z + v.w * v.w;
#pragma unroll
    for (int m = 1; m < 32; m <<= 1) ss += __shfl_xor(ss, m, 32);
    float r = rsqrtf(ss * (1.0f / 128.0f) + EPSF);
    float4 g = gp[tid];
    float4 wv = ((const float4*)w)[tid & 31];
    ushort4 out;
    out.x = f2bf(v.x * r * wv.x * siluf(g.x));
    out.y = f2bf(v.y * r * wv.y * siluf(g.y));
    out.z = f2bf(v.z * r * wv.z * siluf(g.z));
    out.w = f2bf(v.w * r * wv.w * siluf(g.w));
    ((ushort4*)(ob + (size_t)row * DIM))[tid] = out;
}

// ---------------- small projections: beta = sigm(h@Wb), alpha = exp(g) ----------------
__global__ void smallproj_kernel(const unsigned short* __restrict__ hbuf,
                                 const float* __restrict__ Wb, const float* __restrict__ Wa,
                                 const float* __restrict__ A_log, const float* __restrict__ dt_bias,
                                 float* __restrict__ Alpha, float* __restrict__ Beta) {
    int row = blockIdx.x;
    int tid = threadIdx.x;  // 128
    __shared__ __align__(16) float hrow[1024];
    __shared__ float part[128];
    const ushort4* h4 = (const ushort4*)(hbuf + (size_t)row * DIM);
    ushort4 u0 = h4[tid * 2], u1 = h4[tid * 2 + 1];
    hrow[tid * 8 + 0] = bf2f(u0.x); hrow[tid * 8 + 1] = bf2f(u0.y);
    hrow[tid * 8 + 2] = bf2f(u0.z); hrow[tid * 8 + 3] = bf2f(u0.w);
    hrow[tid * 8 + 4] = bf2f(u1.x); hrow[tid * 8 + 5] = bf2f(u1.y);
    hrow[tid * 8 + 6] = bf2f(u1.z); hrow[tid * 8 + 7] = bf2f(u1.w);
    __syncthreads();
    int out = tid & 15, slice = tid >> 4;
    const float* W = (out < 8) ? Wb : Wa;
    int col = out & 7;
    int k0 = slice * 128;
    float p = 0.0f;
    for (int kk = 0; kk < 128; kk++) p += hrow[k0 + kk] * W[(size_t)(k0 + kk) * 8 + col];
    part[tid] = p;
    __syncthreads();
    if (tid < 16) {
        float sum = 0.0f;
#pragma unroll
        for (int sl = 0; sl < 8; sl++) sum += part[sl * 16 + tid];
        if (tid < 8) {
            Beta[(size_t)row * 8 + tid] = 1.0f / (1.0f + expf(-sum));
        } else {
            int hh = tid - 8;
            float xg = sum + dt_bias[hh];
            float sp = fmaxf(xg, 0.0f) + log1pf(expf(-fabsf(xg)));
            Alpha[(size_t)row * 8 + hh] = expf(-expf(A_log[hh]) * sp);
        }
    }
}

// ---------------- gated delta-rule scan ----------------
// 256 blocks: (b,h) x 8 dv-slices of 16 cols. 128 threads: lane&7 = dk-slice(16),
// tid>>3 = dv column. Per-thread state s[16] in VGPRs; shfl-reduce over 8 lanes;
// register prefetch of next timestep; no barriers.
__global__ __launch_bounds__(128) void scan_kernel(
    const float* __restrict__ Q, const float* __restrict__ Kb,
    const float* __restrict__ V, const float* __restrict__ Alpha,
    const float* __restrict__ Beta, float* __restrict__ O) {
    int blk = blockIdx.x;
    int bh = blk >> 3, dvb = blk & 7;
    int b = bh >> 3, h = bh & 7;
    int tid = threadIdx.x;
    int ks = tid & 7;        // dk slice [ks*16, ks*16+16)
    int dvl = tid >> 3;      // 0..15
    int col_k = h * 128 + ks * 16;
    int col_v = h * 128 + dvb * 16 + dvl;
    size_t base0 = (size_t)b * 2048 * DIM;

    const float4* Kp = (const float4*)(Kb + base0 + col_k);
    const float4* Qp = (const float4*)(Q + base0 + col_k);
    const float* Vp = V + base0 + col_v;
    const float* Ap = Alpha + (size_t)b * 2048 * 8 + h;
    const float* Bp = Beta + (size_t)b * 2048 * 8 + h;
    float* Op = O + base0 + col_v;

    float s[16];
#pragma unroll
    for (int i = 0; i < 16; i++) s[i] = 0.0f;

    const float scale = 0.08838834764831845f;

    float4 ka0 = Kp[0], ka1 = Kp[1], ka2 = Kp[2], ka3 = Kp[3];
    float4 qa0 = Qp[0], qa1 = Qp[1], qa2 = Qp[2], qa3 = Qp[3];
    float va = Vp[0], aa = Ap[0], ba = Bp[0];

#pragma unroll 2
    for (int t = 0; t < 2048; ++t) {
        int tn = (t + 1 < 2048) ? (t + 1) : t;
        size_t ro = (size_t)tn * 256;  // float4 row stride
        float4 kb0 = Kp[ro + 0], kb1 = Kp[ro + 1], kb2 = Kp[ro + 2], kb3 = Kp[ro + 3];
        float4 qb0 = Qp[ro + 0], qb1 = Qp[ro + 1], qb2 = Qp[ro + 2], qb3 = Qp[ro + 3];
        float vb = Vp[(size_t)tn * DIM], ab = Ap[(size_t)tn * 8], bb = Bp[(size_t)tn * 8];

        // kv = k . S_old (this thread's dk slice)
        float kv0 = fmaf(ka0.x, s[0], fmaf(ka0.y, s[1], fmaf(ka0.z, s[2], ka0.w * s[3])));
        float kv1 = fmaf(ka1.x, s[4], fmaf(ka1.y, s[5], fmaf(ka1.z, s[6], ka1.w * s[7])));
        float kv2 = fmaf(ka2.x, s[8], fmaf(ka2.y, s[9], fmaf(ka2.z, s[10], ka2.w * s[11])));
        float kv3 = fmaf(ka3.x, s[12], fmaf(ka3.y, s[13], fmaf(ka3.z, s[14], ka3.w * s[15])));
        float kv = (kv0 + kv1) + (kv2 + kv3);
        kv += __shfl_xor(kv, 1);
        kv += __shfl_xor(kv, 2);
        kv += __shfl_xor(kv, 4);
        float delta = (va - aa * kv) * ba;

        float o0, o1, o2, o3;
        s[0] = fmaf(ka0.x, delta, aa * s[0]); o0 = qa0.x * s[0];
        s[1] = fmaf(ka0.y, delta, aa * s[1]); o1 = qa0.y * s[1];
        s[2] = fmaf(ka0.z, delta, aa * s[2]); o2 = qa0.z * s[2];
        s[3] = fmaf(ka0.w, delta, aa * s[3]); o3 = qa0.w * s[3];
        s[4] = fmaf(ka1.x, delta, aa * s[4]); o0 = fmaf(qa1.x, s[4], o0);
        s[5] = fmaf(ka1.y, delta, aa * s[5]); o1 = fmaf(qa1.y, s[5], o1);
        s[6] = fmaf(ka1.z, delta, aa * s[6]); o2 = fmaf(qa1.z, s[6], o2);
        s[7] = fmaf(ka1.w, delta, aa * s[7]); o3 = fmaf(qa1.w, s[7], o3);
        s[8] = fmaf(ka2.x, delta, aa * s[8]); o0 = fmaf(qa2.x, s[8], o0);
        s[9] = fmaf(ka2.y, delta, aa * s[9]); o1 = fmaf(qa2.y, s[9], o1);
        s[10] = fmaf(ka2.z, delta, aa * s[10]); o2 = fmaf(qa2.z, s[10], o2);
        s[11] = fmaf(ka2.w, delta, aa * s[11]); o3 = fmaf(qa2.w, s[11], o3);
        s[12] = fmaf(ka3.x, delta, aa * s[12]); o0 = fmaf(qa3.x, s[12], o0);
        s[13] = fmaf(ka3.y, delta, aa * s[13]); o1 = fmaf(qa3.y, s[13], o1);
        s[14] = fmaf(ka3.z, delta, aa * s[14]); o2 = fmaf(qa3.z, s[14], o2);
        s[15] = fmaf(ka3.w, delta, aa * s[15]); o3 = fmaf(qa3.w, s[15], o3);
        float oacc = (o0 + o1) + (o2 + o3);
        oacc += __shfl_xor(oacc, 1);
        oacc += __shfl_xor(oacc, 2);
        oacc += __shfl_xor(oacc, 4);
        if (ks == 0) Op[(size_t)t * DIM] = oacc * scale;

        ka0 = kb0; ka1 = kb1; ka2 = kb2; ka3 = kb3;
        qa0 = qb0; qa1 = qb1; qa2 = qb2; qa3 = qb3;
        va = vb; aa = ab; ba = bb;
    }
}

extern "C" void kernel_launch(void* const* d_in, const int* in_sizes, int n_in,
                              void* d_out, int out_size, void* d_ws, size_t ws_size,
                              hipStream_t stream) {
    const float* x      = (const float*)d_in[0];
    const float* Wq     = (const float*)d_in[1];
    const float* Wk     = (const float*)d_in[2];
    const float* Wv     = (const float*)d_in[3];
    const float* Wb     = (const float*)d_in[4];
    const float* Wa     = (const float*)d_in[5];
    const float* A_log  = (const float*)d_in[6];
    const float* dt_b   = (const float*)d_in[7];
    const float* Wg     = (const float*)d_in[8];
    const float* o_norm = (const float*)d_in[9];
    const float* Wo     = (const float*)d_in[10];
    const float* W_fc   = (const float*)d_in[11];
    const float* W_proj = (const float*)d_in[12];
    float* out = (float*)d_out;

    const size_t MAT = (size_t)ROWS * DIM;
    float* ws = (float*)d_ws;
    float* fq    = ws;                 // q fp32
    float* fk    = ws + MAT;           // k fp32
    float* fv    = ws + 2 * MAT;       // v fp32; later o_bf (ushort)
    float* fgate = ws + 3 * MAT;       // gate fp32
    float* fo    = ws + 4 * MAT;       // h_bf (ushort) -> o fp32 -> m_bf (ushort)
    float* alpha = ws + 5 * MAT;
    float* beta  = alpha + (size_t)ROWS * NH;
    unsigned short* wts = (unsigned short*)(beta + (size_t)ROWS * NH);
    unsigned short* WqT = wts;                    // [1024,1024]
    unsigned short* WkT = wts + (1u << 20);
    unsigned short* WvT = wts + 2 * (1u << 20);
    unsigned short* WgT = wts + 3 * (1u << 20);
    unsigned short* WoT = wts + 4 * (1u << 20);
    unsigned short* WfcT = wts + 5 * (1u << 20);  // [4096,1024]
    unsigned short* WprT = wts + 9 * (1u << 20);  // [1024,4096]
    unsigned short* h_bf = (unsigned short*)fo;
    unsigned short* m_bf = (unsigned short*)fo;
    unsigned short* o_bf = (unsigned short*)fv;
    unsigned short* fc_bf = (unsigned short*)ws;  // spans q+k regions (64MB)

    // 0. weight transposes -> bf16 [N,K]
    transpose_bf16_kernel<<<dim3(32, 32), 256, 0, stream>>>(Wq, WqT, 1024, 1024);
    transpose_bf16_kernel<<<dim3(32, 32), 256, 0, stream>>>(Wk, WkT, 1024, 1024);
    transpose_bf16_kernel<<<dim3(32, 32), 256, 0, stream>>>(Wv, WvT, 1024, 1024);
    transpose_bf16_kernel<<<dim3(32, 32), 256, 0, stream>>>(Wg, WgT, 1024, 1024);
    transpose_bf16_kernel<<<dim3(32, 32), 256, 0, stream>>>(Wo, WoT, 1024, 1024);
    transpose_bf16_kernel<<<dim3(128, 32), 256, 0, stream>>>(W_fc, WfcT, 1024, 4096);
    transpose_bf16_kernel<<<dim3(32, 128), 256, 0, stream>>>(W_proj, WprT, 4096, 1024);

    // 1. h = rms_norm(x) -> bf16
    rmsnorm_bf16_kernel<<<ROWS, 256, 0, stream>>>(x, h_bf);

    // 2. projections (bf16 MFMA, fp32 out)
    dim3 g1(DIM / 128, ROWS / 128);
    mfma_gemm<1, float><<<g1, 256, 0, stream>>>(h_bf, WqT, fq, nullptr, ROWS, DIM, DIM);
    mfma_gemm<1, float><<<g1, 256, 0, stream>>>(h_bf, WkT, fk, nullptr, ROWS, DIM, DIM);
    mfma_gemm<1, float><<<g1, 256, 0, stream>>>(h_bf, WvT, fv, nullptr, ROWS, DIM, DIM);
    mfma_gemm<0, float><<<g1, 256, 0, stream>>>(h_bf, WgT, fgate, nullptr, ROWS, DIM, DIM);

    // 3. l2norm q, k
    l2norm_kernel<<<ROWS, 256, 0, stream>>>(fq);
    l2norm_kernel<<<ROWS, 256, 0, stream>>>(fk);

    // 4. beta/alpha
    smallproj_kernel<<<ROWS, 128, 0, stream>>>(h_bf, Wb, Wa, A_log, dt_b, alpha, beta);

    // 5. delta-rule scan (writes o fp32 into fo, over dead h_bf)
    scan_kernel<<<256, 128, 0, stream>>>(fq, fk, fv, alpha, beta, fo);

    // 6. gated RMSNorm -> o_bf (over dead v)
    gating_kernel<<<ROWS, 256, 0, stream>>>(fo, fgate, o_norm, o_bf);

    // 7. d_out = x + o @ Wo
    mfma_gemm<2, float><<<g1, 256, 0, stream>>>(o_bf, WoT, out, x, ROWS, DIM, DIM);

    // 8. m = rms_norm(d_out) -> m_bf (over dead o)
    rmsnorm_bf16_kernel<<<ROWS, 256, 0, stream>>>(out, m_bf);

    // 9. fc = relu(m @ W_fc)^2 -> bf16 (over dead q,k)
    dim3 g2(DFF_ / 128, ROWS / 128);
    mfma_gemm<3, unsigned short><<<g2, 256, 0, stream>>>(m_bf, WfcT, fc_bf, nullptr, ROWS, DFF_, DIM);

    // 10. d_out += fc @ W_proj
    mfma_gemm<2, float><<<g1, 256, 0, stream>>>(fc_bf, WprT, out, out, ROWS, DIM, DFF_);
}

// Round 3
// 1208.410 us; speedup vs baseline: 7.0703x; 1.3451x over previous
//
#include <hip/hip_runtime.h>
#include <math.h>
#include <stdint.h>

#define ROWS 8192   // B*S
#define DIM  1024
#define NH   8
#define DFF_ 4096
#define EPSF 1e-6f

typedef __attribute__((ext_vector_type(8))) short short8;
typedef __attribute__((ext_vector_type(4))) float f32x4;

__device__ __forceinline__ float siluf(float x) {
    return x / (1.0f + expf(-x));
}
__device__ __forceinline__ unsigned short f2bf(float f) {
    uint32_t u = __float_as_uint(f);
    uint32_t r = (u + 0x7FFFu + ((u >> 16) & 1u)) >> 16;
    return (unsigned short)r;
}
__device__ __forceinline__ float bf2f(unsigned short u) {
    return __uint_as_float(((uint32_t)u) << 16);
}

// async global->LDS 16B (wave-uniform LDS base + lane*16)
__device__ __forceinline__ void async16(const void* g, void* l) {
    __builtin_amdgcn_global_load_lds(
        (const __attribute__((address_space(1))) uint32_t*)g,
        (__attribute__((address_space(3))) uint32_t*)l, 16, 0, 0);
}

// DPP-based 8-lane reduce (lanes grouped at aligned 8-lane boundaries).
// xor1 = quad_perm[1,0,3,2] (0xB1), xor2 = quad_perm[2,3,0,1] (0x4E),
// cross-quad pair = row_half_mirror (0x141). All VALU — no LDS latency.
template <int C>
__device__ __forceinline__ float dpp_add(float x) {
    int y = __builtin_amdgcn_update_dpp(0, __float_as_int(x), C, 0xF, 0xF, true);
    return x + __int_as_float(y);
}
__device__ __forceinline__ float red8(float x) {
    x = dpp_add<0xB1>(x);
    x = dpp_add<0x4E>(x);
    x = dpp_add<0x141>(x);
    return x;
}

// ---------------- RMSNorm -> bf16 out ----------------
__global__ void rmsnorm_bf16_kernel(const float* __restrict__ x, unsigned short* __restrict__ y) {
    int row = blockIdx.x;
    int tid = threadIdx.x;  // 256 threads, one float4 each
    const float4* x4 = (const float4*)(x + (size_t)row * DIM);
    float4 v = x4[tid];
    float ss = v.x * v.x + v.y * v.y + v.z * v.z + v.w * v.w;
#pragma unroll
    for (int m = 1; m < 64; m <<= 1) ss += __shfl_xor(ss, m, 64);
    __shared__ float wss[4];
    if ((tid & 63) == 0) wss[tid >> 6] = ss;
    __syncthreads();
    float tot = wss[0] + wss[1] + wss[2] + wss[3];
    float r = rsqrtf(tot * (1.0f / 1024.0f) + EPSF);
    ushort4 o;
    o.x = f2bf(v.x * r); o.y = f2bf(v.y * r); o.z = f2bf(v.z * r); o.w = f2bf(v.w * r);
    ((ushort4*)(y + (size_t)row * DIM))[tid] = o;
}

// ---------------- fp32 -> bf16 transpose: W[K,N] -> WT[N,K] ----------------
__global__ void transpose_bf16_kernel(const float* __restrict__ W, unsigned short* __restrict__ WT,
                                      int K, int N) {
    __shared__ float tile[32][33];
    int n0 = blockIdx.x * 32, k0 = blockIdx.y * 32;
    int tx = threadIdx.x & 31, ty = threadIdx.x >> 5;  // 256 threads: 32 x 8
#pragma unroll
    for (int r = 0; r < 32; r += 8)
        tile[ty + r][tx] = W[(size_t)(k0 + ty + r) * N + n0 + tx];
    __syncthreads();
#pragma unroll
    for (int r = 0; r < 32; r += 8)
        WT[(size_t)(n0 + ty + r) * K + k0 + tx] = f2bf(tile[tx][ty + r]);
}

// ---------------- bf16 MFMA GEMM: C[M,N] = A[M,K] @ BT[N,K]^T ----------------
// EPI: 0 none(f32), 1 silu(f32), 2 res+acc(f32), 3 relu^2 -> bf16
template <int EPI, typename CT>
__global__ __launch_bounds__(256) void mfma_gemm(
    const unsigned short* __restrict__ A, const unsigned short* __restrict__ BT,
    CT* __restrict__ C, const float* __restrict__ res, int M, int N, int K) {
    __shared__ __align__(16) unsigned short As[128 * 32];
    __shared__ __align__(16) unsigned short Bs[128 * 32];
    int tid = threadIdx.x;
    int w = tid >> 6, lane = tid & 63;

    // XCD-aware swizzle (T1): grid is uniform work; nwg % 8 == 0 for all our launches.
    int nwgx = gridDim.x;
    int nwg = nwgx * gridDim.y;
    int id = blockIdx.y * nwgx + blockIdx.x;
    int cpx = nwg >> 3;
    int nid = (id & 7) * cpx + (id >> 3);
    int bxs = nid % nwgx, bys = nid / nwgx;

    int bm = bys * 128, bn = bxs * 128;
    int wm = (w >> 1) * 64, wn = (w & 1) * 64;

    int srow = tid >> 2;           // 0..63
    int skb = (tid & 3) * 8;       // ushort offset in row (16B chunks)
    const unsigned short* Ag = A + (size_t)(bm + srow) * K + skb;
    const unsigned short* Bg = BT + (size_t)(bn + srow) * K + skb;

    f32x4 acc[4][4] = {};

    int lr = lane & 15;
    int lk = (lane >> 4) * 8;

    for (int kt = 0; kt < K; kt += 32) {
        async16(Ag + kt, As + w * 512);
        async16(Ag + kt + (size_t)64 * K, As + 2048 + w * 512);
        async16(Bg + kt, Bs + w * 512);
        async16(Bg + kt + (size_t)64 * K, Bs + 2048 + w * 512);
        __syncthreads();  // drains vmcnt+lgkmcnt
        short8 af[4], bf[4];
#pragma unroll
        for (int i = 0; i < 4; i++) {
            af[i] = *(const short8*)&As[(wm + i * 16 + lr) * 32 + lk];
            bf[i] = *(const short8*)&Bs[(wn + i * 16 + lr) * 32 + lk];
        }
#pragma unroll
        for (int i = 0; i < 4; i++)
#pragma unroll
            for (int j = 0; j < 4; j++)
                acc[i][j] = __builtin_amdgcn_mfma_f32_16x16x32_bf16(af[i], bf[j], acc[i][j], 0, 0, 0);
        __syncthreads();
    }

#pragma unroll
    for (int i = 0; i < 4; i++) {
        int gr0 = bm + wm + i * 16 + (lane >> 4) * 4;
#pragma unroll
        for (int j = 0; j < 4; j++) {
            int gc = bn + wn + j * 16 + lr;
#pragma unroll
            for (int r = 0; r < 4; r++) {
                float v = acc[i][j][r];
                size_t idx = (size_t)(gr0 + r) * N + gc;
                if (EPI == 1) v = siluf(v);
                else if (EPI == 2) v += res[idx];
                else if (EPI == 3) { float t = fmaxf(v, 0.0f); v = t * t; }
                if constexpr (sizeof(CT) == 2) C[idx] = (CT)f2bf(v);
                else C[idx] = v;
            }
        }
    }
}

// ---------------- l2norm over 128-chunks (in-place fp32) ----------------
__global__ void l2norm_kernel(float* __restrict__ x) {
    int row = blockIdx.x;
    int tid = threadIdx.x;  // 256
    float4* p = (float4*)(x + (size_t)row * DIM);
    float4 v = p[tid];
    float ss = v.x * v.x + v.y * v.y + v.z * v.z + v.w * v.w;
#pragma unroll
    for (int m = 1; m < 32; m <<= 1) ss += __shfl_xor(ss, m, 32);
    float r = rsqrtf(ss + EPSF);
    v.x *= r; v.y *= r; v.z *= r; v.w *= r;
    p[tid] = v;
}

// ---------------- gated RMSNorm -> bf16: ob = rms128(o)*w*silu(gate) ----------------
__global__ void gating_kernel(const float* __restrict__ o, const float* __restrict__ gate,
                              const float* __restrict__ w, unsigned short* __restrict__ ob) {
    int row = blockIdx.x;
    int tid = threadIdx.x;  // 256
    const float4* op = (const float4*)(o + (size_t)row * DIM);
    const float4* gp = (const float4*)(gate + (size_t)row * DIM);
    float4 v = op[tid];
    float ss = v.x * v.x + v.y * v.y + v.z * v.z + v.w * v.w;
#pragma unroll
    for (int m = 1; m < 32; m <<= 1) ss += __shfl_xor(ss, m, 32);
    float r = rsqrtf(ss * (1.0f / 128.0f) + EPSF);
    float4 g = gp[tid];
    float4 wv = ((const float4*)w)[tid & 31];
    ushort4 out;
    out.x = f2bf(v.x * r * wv.x * siluf(g.x));
    out.y = f2bf(v.y * r * wv.y * siluf(g.y));
    out.z = f2bf(v.z * r * wv.z * siluf(g.z));
    out.w = f2bf(v.w * r * wv.w * siluf(g.w));
    ((ushort4*)(ob + (size_t)row * DIM))[tid] = out;
}

// ---------------- small projections: beta = sigm(h@Wb), alpha = exp(g) ----------------
__global__ void smallproj_kernel(const unsigned short* __restrict__ hbuf,
                                 const float* __restrict__ Wb, const float* __restrict__ Wa,
                                 const float* __restrict__ A_log, const float* __restrict__ dt_bias,
                                 float* __restrict__ Alpha, float* __restrict__ Beta) {
    int row = blockIdx.x;
    int tid = threadIdx.x;  // 128
    __shared__ __align__(16) float hrow[1024];
    __shared__ float part[128];
    const ushort4* h4 = (const ushort4*)(hbuf + (size_t)row * DIM);
    ushort4 u0 = h4[tid * 2], u1 = h4[tid * 2 + 1];
    hrow[tid * 8 + 0] = bf2f(u0.x); hrow[tid * 8 + 1] = bf2f(u0.y);
    hrow[tid * 8 + 2] = bf2f(u0.z); hrow[tid * 8 + 3] = bf2f(u0.w);
    hrow[tid * 8 + 4] = bf2f(u1.x); hrow[tid * 8 + 5] = bf2f(u1.y);
    hrow[tid * 8 + 6] = bf2f(u1.z); hrow[tid * 8 + 7] = bf2f(u1.w);
    __syncthreads();
    int out = tid & 15, slice = tid >> 4;
    const float* W = (out < 8) ? Wb : Wa;
    int col = out & 7;
    int k0 = slice * 128;
    float p = 0.0f;
    for (int kk = 0; kk < 128; kk++) p += hrow[k0 + kk] * W[(size_t)(k0 + kk) * 8 + col];
    part[tid] = p;
    __syncthreads();
    if (tid < 16) {
        float sum = 0.0f;
#pragma unroll
        for (int sl = 0; sl < 8; sl++) sum += part[sl * 16 + tid];
        if (tid < 8) {
            Beta[(size_t)row * 8 + tid] = 1.0f / (1.0f + expf(-sum));
        } else {
            int hh = tid - 8;
            float xg = sum + dt_bias[hh];
            float sp = fmaxf(xg, 0.0f) + log1pf(expf(-fabsf(xg)));
            Alpha[(size_t)row * 8 + hh] = expf(-expf(A_log[hh]) * sp);
        }
    }
}

// ---------------- gated delta-rule scan ----------------
// 256 blocks: (b,h) x 8 dv-slices of 16 cols. 128 threads: tid&7 = dk-slice(16),
// tid>>3 = dv column. s[16] in VGPRs; DPP 8-lane reduce (no LDS latency);
// 2-deep register prefetch (named A/B sets, manual unroll-2).
#define SCAN_LOAD(P, tn) do {                                                   \
    size_t ro_ = (size_t)(tn) * 256;                                            \
    P##k0 = Kp[ro_ + 0]; P##k1 = Kp[ro_ + 1];                                   \
    P##k2 = Kp[ro_ + 2]; P##k3 = Kp[ro_ + 3];                                   \
    P##q0 = Qp[ro_ + 0]; P##q1 = Qp[ro_ + 1];                                   \
    P##q2 = Qp[ro_ + 2]; P##q3 = Qp[ro_ + 3];                                   \
    P##v = Vp[(size_t)(tn) * DIM];                                              \
    P##a = Ap[(size_t)(tn) * 8]; P##b = Bp[(size_t)(tn) * 8];                   \
} while (0)

#define SCAN_STEP(P, t) do {                                                    \
    float kv0 = fmaf(P##k0.x, s[0], fmaf(P##k0.y, s[1], fmaf(P##k0.z, s[2], P##k0.w * s[3])));   \
    float kv1 = fmaf(P##k1.x, s[4], fmaf(P##k1.y, s[5], fmaf(P##k1.z, s[6], P##k1.w * s[7])));   \
    float kv2 = fmaf(P##k2.x, s[8], fmaf(P##k2.y, s[9], fmaf(P##k2.z, s[10], P##k2.w * s[11]))); \
    float kv3 = fmaf(P##k3.x, s[12], fmaf(P##k3.y, s[13], fmaf(P##k3.z, s[14], P##k3.w * s[15])));\
    float kv = red8((kv0 + kv1) + (kv2 + kv3));                                 \
    float delta = (P##v - P##a * kv) * P##b;                                    \
    float o0, o1, o2, o3;                                                       \
    s[0]  = fmaf(P##k0.x, delta, P##a * s[0]);  o0 = P##q0.x * s[0];            \
    s[1]  = fmaf(P##k0.y, delta, P##a * s[1]);  o1 = P##q0.y * s[1];            \
    s[2]  = fmaf(P##k0.z, delta, P##a * s[2]);  o2 = P##q0.z * s[2];            \
    s[3]  = fmaf(P##k0.w, delta, P##a * s[3]);  o3 = P##q0.w * s[3];            \
    s[4]  = fmaf(P##k1.x, delta, P##a * s[4]);  o0 = fmaf(P##q1.x, s[4], o0);   \
    s[5]  = fmaf(P##k1.y, delta, P##a * s[5]);  o1 = fmaf(P##q1.y, s[5], o1);   \
    s[6]  = fmaf(P##k1.z, delta, P##a * s[6]);  o2 = fmaf(P##q1.z, s[6], o2);   \
    s[7]  = fmaf(P##k1.w, delta, P##a * s[7]);  o3 = fmaf(P##q1.w, s[7], o3);   \
    s[8]  = fmaf(P##k2.x, delta, P##a * s[8]);  o0 = fmaf(P##q2.x, s[8], o0);   \
    s[9]  = fmaf(P##k2.y, delta, P##a * s[9]);  o1 = fmaf(P##q2.y, s[9], o1);   \
    s[10] = fmaf(P##k2.z, delta, P##a * s[10]); o2 = fmaf(P##q2.z, s[10], o2);  \
    s[11] = fmaf(P##k2.w, delta, P##a * s[11]); o3 = fmaf(P##q2.w, s[11], o3);  \
    s[12] = fmaf(P##k3.x, delta, P##a * s[12]); o0 = fmaf(P##q3.x, s[12], o0);  \
    s[13] = fmaf(P##k3.y, delta, P##a * s[13]); o1 = fmaf(P##q3.y, s[13], o1);  \
    s[14] = fmaf(P##k3.z, delta, P##a * s[14]); o2 = fmaf(P##q3.z, s[14], o2);  \
    s[15] = fmaf(P##k3.w, delta, P##a * s[15]); o3 = fmaf(P##q3.w, s[15], o3);  \
    float oacc = red8((o0 + o1) + (o2 + o3));                                   \
    if (ks == 0) Op[(size_t)(t) * DIM] = oacc * scale;                          \
} while (0)

__global__ __launch_bounds__(128) void scan_kernel(
    const float* __restrict__ Q, const float* __restrict__ Kb,
    const float* __restrict__ V, const float* __restrict__ Alpha,
    const float* __restrict__ Beta, float* __restrict__ O) {
    int blk = blockIdx.x;
    int bh = blk >> 3, dvb = blk & 7;
    int b = bh >> 3, h = bh & 7;
    int tid = threadIdx.x;
    int ks = tid & 7;        // dk slice [ks*16, ks*16+16)
    int dvl = tid >> 3;      // 0..15
    int col_k = h * 128 + ks * 16;
    int col_v = h * 128 + dvb * 16 + dvl;
    size_t base0 = (size_t)b * 2048 * DIM;

    const float4* Kp = (const float4*)(Kb + base0 + col_k);
    const float4* Qp = (const float4*)(Q + base0 + col_k);
    const float* Vp = V + base0 + col_v;
    const float* Ap = Alpha + (size_t)b * 2048 * 8 + h;
    const float* Bp = Beta + (size_t)b * 2048 * 8 + h;
    float* Op = O + base0 + col_v;

    float s[16];
#pragma unroll
    for (int i = 0; i < 16; i++) s[i] = 0.0f;

    const float scale = 0.08838834764831845f;

    float4 Ak0, Ak1, Ak2, Ak3, Aq0, Aq1, Aq2, Aq3;
    float Av, Aa, Ab;
    float4 Bk0, Bk1, Bk2, Bk3, Bq0, Bq1, Bq2, Bq3;
    float Bv, Ba, Bb;

    SCAN_LOAD(A, 0);
    SCAN_LOAD(B, 1);

    int t = 0;
    for (; t < 2046; t += 2) {
        SCAN_STEP(A, t);        // consume A (step t)
        SCAN_LOAD(A, t + 2);    // refill A for step t+2 (in flight ~2 iters)
        SCAN_STEP(B, t + 1);    // consume B (step t+1)
        SCAN_LOAD(B, t + 3);    // refill B for step t+3
    }
    SCAN_STEP(A, 2046);
    SCAN_STEP(B, 2047);
}

extern "C" void kernel_launch(void* const* d_in, const int* in_sizes, int n_in,
                              void* d_out, int out_size, void* d_ws, size_t ws_size,
                              hipStream_t stream) {
    const float* x      = (const float*)d_in[0];
    const float* Wq     = (const float*)d_in[1];
    const float* Wk     = (const float*)d_in[2];
    const float* Wv     = (const float*)d_in[3];
    const float* Wb     = (const float*)d_in[4];
    const float* Wa     = (const float*)d_in[5];
    const float* A_log  = (const float*)d_in[6];
    const float* dt_b   = (const float*)d_in[7];
    const float* Wg     = (const float*)d_in[8];
    const float* o_norm = (const float*)d_in[9];
    const float* Wo     = (const float*)d_in[10];
    const float* W_fc   = (const float*)d_in[11];
    const float* W_proj = (const float*)d_in[12];
    float* out = (float*)d_out;

    const size_t MAT = (size_t)ROWS * DIM;
    float* ws = (float*)d_ws;
    float* fq    = ws;                 // q fp32
    float* fk    = ws + MAT;           // k fp32
    float* fv    = ws + 2 * MAT;       // v fp32; later o_bf (ushort)
    float* fgate = ws + 3 * MAT;       // gate fp32
    float* fo    = ws + 4 * MAT;       // h_bf (ushort) -> o fp32 -> m_bf (ushort)
    float* alpha = ws + 5 * MAT;
    float* beta  = alpha + (size_t)ROWS * NH;
    unsigned short* wts = (unsigned short*)(beta + (size_t)ROWS * NH);
    unsigned short* WqT = wts;                    // [1024,1024]
    unsigned short* WkT = wts + (1u << 20);
    unsigned short* WvT = wts + 2 * (1u << 20);
    unsigned short* WgT = wts + 3 * (1u << 20);
    unsigned short* WoT = wts + 4 * (1u << 20);
    unsigned short* WfcT = wts + 5 * (1u << 20);  // [4096,1024]
    unsigned short* WprT = wts + 9 * (1u << 20);  // [1024,4096]
    unsigned short* h_bf = (unsigned short*)fo;
    unsigned short* m_bf = (unsigned short*)fo;
    unsigned short* o_bf = (unsigned short*)fv;
    unsigned short* fc_bf = (unsigned short*)ws;  // spans q+k regions (64MB)

    // 0. weight transposes -> bf16 [N,K]
    transpose_bf16_kernel<<<dim3(32, 32), 256, 0, stream>>>(Wq, WqT, 1024, 1024);
    transpose_bf16_kernel<<<dim3(32, 32), 256, 0, stream>>>(Wk, WkT, 1024, 1024);
    transpose_bf16_kernel<<<dim3(32, 32), 256, 0, stream>>>(Wv, WvT, 1024, 1024);
    transpose_bf16_kernel<<<dim3(32, 32), 256, 0, stream>>>(Wg, WgT, 1024, 1024);
    transpose_bf16_kernel<<<dim3(32, 32), 256, 0, stream>>>(Wo, WoT, 1024, 1024);
    transpose_bf16_kernel<<<dim3(128, 32), 256, 0, stream>>>(W_fc, WfcT, 1024, 4096);
    transpose_bf16_kernel<<<dim3(32, 128), 256, 0, stream>>>(W_proj, WprT, 4096, 1024);

    // 1. h = rms_norm(x) -> bf16
    rmsnorm_bf16_kernel<<<ROWS, 256, 0, stream>>>(x, h_bf);

    // 2. projections (bf16 MFMA, fp32 out)
    dim3 g1(DIM / 128, ROWS / 128);
    mfma_gemm<1, float><<<g1, 256, 0, stream>>>(h_bf, WqT, fq, nullptr, ROWS, DIM, DIM);
    mfma_gemm<1, float><<<g1, 256, 0, stream>>>(h_bf, WkT, fk, nullptr, ROWS, DIM, DIM);
    mfma_gemm<1, float><<<g1, 256, 0, stream>>>(h_bf, WvT, fv, nullptr, ROWS, DIM, DIM);
    mfma_gemm<0, float><<<g1, 256, 0, stream>>>(h_bf, WgT, fgate, nullptr, ROWS, DIM, DIM);

    // 3. l2norm q, k
    l2norm_kernel<<<ROWS, 256, 0, stream>>>(fq);
    l2norm_kernel<<<ROWS, 256, 0, stream>>>(fk);

    // 4. beta/alpha
    smallproj_kernel<<<ROWS, 128, 0, stream>>>(h_bf, Wb, Wa, A_log, dt_b, alpha, beta);

    // 5. delta-rule scan (writes o fp32 into fo, over dead h_bf)
    scan_kernel<<<256, 128, 0, stream>>>(fq, fk, fv, alpha, beta, fo);

    // 6. gated RMSNorm -> o_bf (over dead v)
    gating_kernel<<<ROWS, 256, 0, stream>>>(fo, fgate, o_norm, o_bf);

    // 7. d_out = x + o @ Wo
    mfma_gemm<2, float><<<g1, 256, 0, stream>>>(o_bf, WoT, out, x, ROWS, DIM, DIM);

    // 8. m = rms_norm(d_out) -> m_bf (over dead o)
    rmsnorm_bf16_kernel<<<ROWS, 256, 0, stream>>>(out, m_bf);

    // 9. fc = relu(m @ W_fc)^2 -> bf16 (over dead q,k)
    dim3 g2(DFF_ / 128, ROWS / 128);
    mfma_gemm<3, unsigned short><<<g2, 256, 0, stream>>>(m_bf, WfcT, fc_bf, nullptr, ROWS, DFF_, DIM);

    // 10. d_out += fc @ W_proj
    mfma_gemm<2, float><<<g1, 256, 0, stream>>>(fc_bf, WprT, out, out, ROWS, DIM, DFF_);
}